// Round 6
// baseline (166.551 us; speedup 1.0000x reference)
//
#include <hip/hip_runtime.h>

// Problem constants: B=64, T=8192, L=64, NWIN=8128
// Single launch, one block per batch: 64 blocks x 1024 threads, no workspace,
// no atomics, no second dispatch. Round-2's structure failed ONLY because of
// register spills (indexed arrays -> scratch); here the hot loop is the
// round-4-proven named-scalar form: 8 windows/thread, j chunked by 8, live set
// ~50 VGPR (8 acc + 16 x + 8 y) -> unspillable even at a 64-reg allocation.
// WPT=8 makes LDS reads stride-2-float4 (8-way bank conflict, 2.94x per m136),
// so the XOR float4-index swizzle is applied on BOTH store and load
// (involution): each 8-lane group then covers all 32 banks exactly once ->
// conflict-free ds_read_b128 floor.
constexpr int B_SZ = 64;
constexpr int T_SZ = 8192;
constexpr int L_SZ = 64;
constexpr int NWIN = T_SZ - L_SZ;    // 8128
constexpr int NTHR = 1024;
constexpr int WPT  = 8;              // 1016 active threads * 8 = 8128 windows
constexpr int NW   = NTHR / 64;      // 16 waves

__device__ __forceinline__ int swz(int i) { return i ^ ((i >> 3) & 7); }

#define STEP(ACC, XV, YV) { const float t_ = (XV) - (YV); ACC = fmaf(t_, t_, ACC); }
#define WIN8(ACC, A,B,C,D,E,F,G,H) \
    STEP(ACC, A, y0) STEP(ACC, B, y1) STEP(ACC, C, y2) STEP(ACC, D, y3) \
    STEP(ACC, E, y4) STEP(ACC, F, y5) STEP(ACC, G, y6) STEP(ACC, H, y7)

__global__ __launch_bounds__(NTHR, 4)
void window_match_one(const float* __restrict__ X_in,
                      const float* __restrict__ X_out,
                      float* __restrict__ out)
{
    __shared__ float xs[T_SZ];                 // 32 KB, swizzled float4 layout
    __shared__ float ysh[L_SZ];
    __shared__ unsigned long long wred[NW];
    __shared__ int s_win;

    const int b   = blockIdx.x;
    const int tid = threadIdx.x;

    // Stage full row: 2048 float4 over 1024 threads = 2 rounds.
    // Global side linear/coalesced; LDS slot permuted by swz (consecutive
    // lanes stay in distinct banks on the store side too).
    const float4* xg  = reinterpret_cast<const float4*>(X_in + (size_t)b * T_SZ);
    float4*       xs4 = reinterpret_cast<float4*>(xs);
    xs4[swz(tid)]        = xg[tid];
    xs4[swz(tid + NTHR)] = xg[tid + NTHR];
    if (tid < L_SZ) ysh[tid] = X_out[(size_t)b * L_SZ + tid];
    __syncthreads();

    unsigned long long best = ~0ull;
    if (tid < NWIN / WPT) {                    // tid < 1016
        float a0 = 0.0f, a1 = 0.0f, a2 = 0.0f, a3 = 0.0f;
        float a4 = 0.0f, a5 = 0.0f, a6 = 0.0f, a7 = 0.0f;
        const float4* xr = reinterpret_cast<const float4*>(xs);
        const float4* yr = reinterpret_cast<const float4*>(ysh);
        const int f0 = 2 * tid;                // float4 index of s0 = 8*tid

        // j chunked by 8: per chunk 2 broadcast y-reads (free) + 4 swizzled
        // b128 x-reads covering floats [8*tid+8jc .. +8jc+15] (windows need +14).
        #pragma unroll
        for (int jc = 0; jc < L_SZ / 8; ++jc) {
            const float4 ya = yr[2 * jc];
            const float4 yb = yr[2 * jc + 1];
            const float y0 = ya.x, y1 = ya.y, y2 = ya.z, y3 = ya.w;
            const float y4 = yb.x, y5 = yb.y, y6 = yb.z, y7 = yb.w;

            const float4 xa = xr[swz(f0 + 2 * jc + 0)];
            const float4 xb = xr[swz(f0 + 2 * jc + 1)];
            const float4 xc = xr[swz(f0 + 2 * jc + 2)];
            const float4 xd = xr[swz(f0 + 2 * jc + 3)];
            const float x0  = xa.x, x1  = xa.y, x2  = xa.z, x3  = xa.w;
            const float x4  = xb.x, x5  = xb.y, x6  = xb.z, x7  = xb.w;
            const float x8  = xc.x, x9  = xc.y, x10 = xc.z, x11 = xc.w;
            const float x12 = xd.x, x13 = xd.y, x14 = xd.z;

            WIN8(a0, x0, x1, x2,  x3,  x4,  x5,  x6,  x7)
            WIN8(a1, x1, x2, x3,  x4,  x5,  x6,  x7,  x8)
            WIN8(a2, x2, x3, x4,  x5,  x6,  x7,  x8,  x9)
            WIN8(a3, x3, x4, x5,  x6,  x7,  x8,  x9,  x10)
            WIN8(a4, x4, x5, x6,  x7,  x8,  x9,  x10, x11)
            WIN8(a5, x5, x6, x7,  x8,  x9,  x10, x11, x12)
            WIN8(a6, x6, x7, x8,  x9,  x10, x11, x12, x13)
            WIN8(a7, x7, x8, x9,  x10, x11, x12, x13, x14)
        }

        // Packed key: ((float_bits(d)<<32)|idx) — d>=0 so u64 order ==
        // (dist, idx) lexicographic, ties -> smallest index == np.argmin.
        const int g0 = WPT * tid;
        unsigned long long k;
        k = ((unsigned long long)__float_as_uint(a0) << 32) | (unsigned int)(g0 + 0); best = k;
        k = ((unsigned long long)__float_as_uint(a1) << 32) | (unsigned int)(g0 + 1); best = k < best ? k : best;
        k = ((unsigned long long)__float_as_uint(a2) << 32) | (unsigned int)(g0 + 2); best = k < best ? k : best;
        k = ((unsigned long long)__float_as_uint(a3) << 32) | (unsigned int)(g0 + 3); best = k < best ? k : best;
        k = ((unsigned long long)__float_as_uint(a4) << 32) | (unsigned int)(g0 + 4); best = k < best ? k : best;
        k = ((unsigned long long)__float_as_uint(a5) << 32) | (unsigned int)(g0 + 5); best = k < best ? k : best;
        k = ((unsigned long long)__float_as_uint(a6) << 32) | (unsigned int)(g0 + 6); best = k < best ? k : best;
        k = ((unsigned long long)__float_as_uint(a7) << 32) | (unsigned int)(g0 + 7); best = k < best ? k : best;
    }

    // Wave (64-lane) shuffle reduce, then cross-wave (16 waves) via LDS.
    #pragma unroll
    for (int off = 32; off > 0; off >>= 1) {
        const unsigned long long o = __shfl_down(best, off, 64);
        best = o < best ? o : best;
    }
    if ((tid & 63) == 0) wred[tid >> 6] = best;
    __syncthreads();

    if (tid == 0) {
        unsigned long long m = wred[0];
        #pragma unroll
        for (int wv = 1; wv < NW; ++wv) {
            const unsigned long long o = wred[wv];
            m = o < m ? o : m;
        }
        s_win = (int)(m & 0xffffffffu);
    }
    __syncthreads();

    // Same block gathers: bit-exact copy of the winning window from global
    // (avoids un-swizzling LDS; 256 B read per block is negligible).
    if (tid < L_SZ)
        out[(size_t)b * L_SZ + tid] = X_in[(size_t)b * T_SZ + s_win + tid];
}

extern "C" void kernel_launch(void* const* d_in, const int* in_sizes, int n_in,
                              void* d_out, int out_size, void* d_ws, size_t ws_size,
                              hipStream_t stream) {
    // Input order: feats_in (unused), X_in, feats_out (unused), X_out
    const float* X_in  = (const float*)d_in[1];
    const float* X_out = (const float*)d_in[3];
    float* out = (float*)d_out;

    window_match_one<<<B_SZ, NTHR, 0, stream>>>(X_in, X_out, out);
}

// Round 7
// 65.761 us; speedup vs baseline: 2.5327x; 2.5327x over previous
//
#include <hip/hip_runtime.h>

// Problem constants: B=64, T=8192, L=64, NWIN=8128
// Single launch, one block per batch: 64 blocks x 1024 threads, no workspace,
// no atomics. Round-6 post-mortem: full unroll of the jc loop let the
// scheduler hoist ds_reads above their FMAs, blowing the live set past the
// compiler's self-chosen 64-VGPR budget -> 94 MB spill traffic. Two fixes:
//   (1) #pragma unroll 1 on the jc loop (live set ~46 regs per iteration,
//       hoisting window bounded);
//   (2) amdgpu_waves_per_eu(4,4): max=4 waves/EU forbids the 8-wave/EU
//       register target (the observed 64-reg heuristic), allowing 128 VGPRs.
// Inner loop is the round-4/5-proven named-scalar form (8 windows/thread,
// j chunked by 8). XOR float4-index swizzle on BOTH LDS store and load
// (involution) spreads the stride-2-float4 read pattern across banks.
constexpr int B_SZ = 64;
constexpr int T_SZ = 8192;
constexpr int L_SZ = 64;
constexpr int NWIN = T_SZ - L_SZ;    // 8128
constexpr int NTHR = 1024;
constexpr int WPT  = 8;              // 1016 active threads * 8 = 8128 windows
constexpr int NW   = NTHR / 64;      // 16 waves

__device__ __forceinline__ int swz(int i) { return i ^ ((i >> 3) & 7); }

#define STEP(ACC, XV, YV) { const float t_ = (XV) - (YV); ACC = fmaf(t_, t_, ACC); }
#define WIN8(ACC, A,B,C,D,E,F,G,H) \
    STEP(ACC, A, y0) STEP(ACC, B, y1) STEP(ACC, C, y2) STEP(ACC, D, y3) \
    STEP(ACC, E, y4) STEP(ACC, F, y5) STEP(ACC, G, y6) STEP(ACC, H, y7)

__global__ __launch_bounds__(NTHR)
__attribute__((amdgpu_waves_per_eu(4, 4)))
void window_match_one(const float* __restrict__ X_in,
                      const float* __restrict__ X_out,
                      float* __restrict__ out)
{
    __shared__ float xs[T_SZ];                 // 32 KB, swizzled float4 layout
    __shared__ float ysh[L_SZ];
    __shared__ unsigned long long wred[NW];
    __shared__ int s_win;

    const int b   = blockIdx.x;
    const int tid = threadIdx.x;

    // Stage full row: 2048 float4 over 1024 threads = 2 rounds.
    // Global side linear/coalesced; LDS slot permuted by swz.
    const float4* xg  = reinterpret_cast<const float4*>(X_in + (size_t)b * T_SZ);
    float4*       xs4 = reinterpret_cast<float4*>(xs);
    xs4[swz(tid)]        = xg[tid];
    xs4[swz(tid + NTHR)] = xg[tid + NTHR];
    if (tid < L_SZ) ysh[tid] = X_out[(size_t)b * L_SZ + tid];
    __syncthreads();

    unsigned long long best = ~0ull;
    if (tid < NWIN / WPT) {                    // tid < 1016
        float a0 = 0.0f, a1 = 0.0f, a2 = 0.0f, a3 = 0.0f;
        float a4 = 0.0f, a5 = 0.0f, a6 = 0.0f, a7 = 0.0f;
        const float4* xr = reinterpret_cast<const float4*>(xs);
        const float4* yr = reinterpret_cast<const float4*>(ysh);
        const int f0 = 2 * tid;                // float4 index of s0 = 8*tid

        // j chunked by 8; NOT unrolled (bounds the live set / hoist window).
        // Per iter: 2 broadcast y-reads + 4 swizzled b128 x-reads covering
        // floats [8*tid+8jc .. +8jc+15] (windows need +14).
        #pragma unroll 1
        for (int jc = 0; jc < L_SZ / 8; ++jc) {
            const float4 ya = yr[2 * jc];
            const float4 yb = yr[2 * jc + 1];
            const float y0 = ya.x, y1 = ya.y, y2 = ya.z, y3 = ya.w;
            const float y4 = yb.x, y5 = yb.y, y6 = yb.z, y7 = yb.w;

            const float4 xa = xr[swz(f0 + 2 * jc + 0)];
            const float4 xb = xr[swz(f0 + 2 * jc + 1)];
            const float4 xc = xr[swz(f0 + 2 * jc + 2)];
            const float4 xd = xr[swz(f0 + 2 * jc + 3)];
            const float x0  = xa.x, x1  = xa.y, x2  = xa.z, x3  = xa.w;
            const float x4  = xb.x, x5  = xb.y, x6  = xb.z, x7  = xb.w;
            const float x8  = xc.x, x9  = xc.y, x10 = xc.z, x11 = xc.w;
            const float x12 = xd.x, x13 = xd.y, x14 = xd.z;

            WIN8(a0, x0, x1, x2,  x3,  x4,  x5,  x6,  x7)
            WIN8(a1, x1, x2, x3,  x4,  x5,  x6,  x7,  x8)
            WIN8(a2, x2, x3, x4,  x5,  x6,  x7,  x8,  x9)
            WIN8(a3, x3, x4, x5,  x6,  x7,  x8,  x9,  x10)
            WIN8(a4, x4, x5, x6,  x7,  x8,  x9,  x10, x11)
            WIN8(a5, x5, x6, x7,  x8,  x9,  x10, x11, x12)
            WIN8(a6, x6, x7, x8,  x9,  x10, x11, x12, x13)
            WIN8(a7, x7, x8, x9,  x10, x11, x12, x13, x14)
        }

        // Packed key: ((float_bits(d)<<32)|idx) — d>=0 so u64 order ==
        // (dist, idx) lexicographic, ties -> smallest index == np.argmin.
        const int g0 = WPT * tid;
        unsigned long long k;
        k = ((unsigned long long)__float_as_uint(a0) << 32) | (unsigned int)(g0 + 0); best = k;
        k = ((unsigned long long)__float_as_uint(a1) << 32) | (unsigned int)(g0 + 1); best = k < best ? k : best;
        k = ((unsigned long long)__float_as_uint(a2) << 32) | (unsigned int)(g0 + 2); best = k < best ? k : best;
        k = ((unsigned long long)__float_as_uint(a3) << 32) | (unsigned int)(g0 + 3); best = k < best ? k : best;
        k = ((unsigned long long)__float_as_uint(a4) << 32) | (unsigned int)(g0 + 4); best = k < best ? k : best;
        k = ((unsigned long long)__float_as_uint(a5) << 32) | (unsigned int)(g0 + 5); best = k < best ? k : best;
        k = ((unsigned long long)__float_as_uint(a6) << 32) | (unsigned int)(g0 + 6); best = k < best ? k : best;
        k = ((unsigned long long)__float_as_uint(a7) << 32) | (unsigned int)(g0 + 7); best = k < best ? k : best;
    }

    // Wave (64-lane) shuffle reduce, then cross-wave (16 waves) via LDS.
    #pragma unroll
    for (int off = 32; off > 0; off >>= 1) {
        const unsigned long long o = __shfl_down(best, off, 64);
        best = o < best ? o : best;
    }
    if ((tid & 63) == 0) wred[tid >> 6] = best;
    __syncthreads();

    if (tid == 0) {
        unsigned long long m = wred[0];
        #pragma unroll
        for (int wv = 1; wv < NW; ++wv) {
            const unsigned long long o = wred[wv];
            m = o < m ? o : m;
        }
        s_win = (int)(m & 0xffffffffu);
    }
    __syncthreads();

    // Same block gathers: bit-exact copy of the winning window from global
    // (avoids un-swizzling LDS; 256 B per block is negligible).
    if (tid < L_SZ)
        out[(size_t)b * L_SZ + tid] = X_in[(size_t)b * T_SZ + s_win + tid];
}

extern "C" void kernel_launch(void* const* d_in, const int* in_sizes, int n_in,
                              void* d_out, int out_size, void* d_ws, size_t ws_size,
                              hipStream_t stream) {
    // Input order: feats_in (unused), X_in, feats_out (unused), X_out
    const float* X_in  = (const float*)d_in[1];
    const float* X_out = (const float*)d_in[3];
    float* out = (float*)d_out;

    window_match_one<<<B_SZ, NTHR, 0, stream>>>(X_in, X_out, out);
}